// Round 9
// baseline (401.066 us; speedup 1.0000x reference)
//
#include <hip/hip_runtime.h>

// RGCN: hetero 2-layer GraphConv (mean aggr), MI355X.
// R13: fill the idle machine. pre_gemm is pinned at ~51us across three
// structures (R10 TLP / R11 pipeline / R12 clamped loads) -- latency-bound
// at 13% occupancy, 2.3 waves/SIMD; the grid can't generate MLP. Fix:
// merge the INDEPENDENT binA edge-binning pass into the same dispatch
// ([pre_u | pre_i | binA x2]); its ~2000 waves fill pre's idle slots.
// Enabler: GEMMs now load fp32 weights directly + convert to bf16
// fragments in-register (same f2bf RNE; wroot +I folded with static-index
// predicated adds), deleting k_wconv and its wb buffer (dependency gone).
// Gather (R12 8B-lane), CSR build (R9 slotted), conv/postlin unchanged
// except fp32-direct W.

#define FDIM 64
typedef unsigned short u16;
typedef unsigned int u32;
typedef __bf16 bf16x8 __attribute__((ext_vector_type(8)));
typedef float f32x4 __attribute__((ext_vector_type(4)));
typedef float f32x2 __attribute__((ext_vector_type(2)));
typedef unsigned int u32x2 __attribute__((ext_vector_type(2)));
typedef unsigned short u16x8v __attribute__((ext_vector_type(8)));

#define SLOT_S 3072
#define TPB_G 4

__device__ __forceinline__ u16 f2bf(float x) {  // RNE
  u32 b = __builtin_bit_cast(u32, x);
  b += 0x7FFFu + ((b >> 16) & 1u);
  return (u16)(b >> 16);
}
__device__ __forceinline__ float blo(u32 p) { return __builtin_bit_cast(float, p << 16); }
__device__ __forceinline__ float bhi(u32 p) { return __builtin_bit_cast(float, p & 0xffff0000u); }
__device__ __forceinline__ bf16x8 pack_bf8(f32x4 lo, f32x4 hi) {
  u16x8v r;
#pragma unroll
  for (int i = 0; i < 4; ++i) { r[i] = f2bf(lo[i]); r[4 + i] = f2bf(hi[i]); }
  return __builtin_bit_cast(bf16x8, r);
}

// ---- init binA cursors to slot bases + zero csr pads ----
__global__ __launch_bounds__(256) void k_init_gcurb(int* __restrict__ gA, int nA,
                                                    int* __restrict__ gB, int nB,
                                                    int* __restrict__ padA,
                                                    int* __restrict__ padB) {
  int i = blockIdx.x * 256 + threadIdx.x;
  if (i < nA) gA[i] = i * SLOT_S;
  else if (i < nA + nB) gB[i - nA] = (i - nA) * SLOT_S;
  if (i < 16) { padA[i] = 0; padB[i] = 0; }
}

// ---- bucket scan (post-binA): counts = gcurb[b]-b*S, exclusive scan ----
__global__ __launch_bounds__(512) void k_bscan2(const int* __restrict__ gcA, int nbA,
                                                const int* __restrict__ gcB, int nbB,
                                                int* __restrict__ boffA,
                                                int* __restrict__ boffB) {
  __shared__ int sd[512];
  int t = threadIdx.x;
  for (int side = 0; side < 2; ++side) {
    const int* gc = side ? gcB : gcA;
    int nb = side ? nbB : nbA;
    int v = (t < nb) ? gc[t] - t * SLOT_S : 0;
    sd[t] = v; __syncthreads();
    int sum = v;
    for (int o = 1; o < 512; o <<= 1) {
      int x = (t >= o) ? sd[t - o] : 0;
      __syncthreads();
      sum += x; sd[t] = sum;
      __syncthreads();
    }
    int* bo = side ? boffB : boffA;
    if (t < nb) bo[t] = sum - v;
    if (t == nb - 1) bo[nb] = sum;
    __syncthreads();
  }
}

// ---- binA body: bin edges into per-bucket slot regions ----
#define PA_C 4096
struct BinASide {
  const int* src; const int* dst; int shift; int nb; int* gcurb; int2* aux;
};
__device__ __forceinline__ void binA_body(const BinASide& P, int bid, int E) {
  __shared__ int cnt[512];
  __shared__ int base[512];
  int t = threadIdx.x;
  int e0 = bid * PA_C;
  int n = min(PA_C, E - e0);
  int nb = P.nb, shift = P.shift;
  for (int b = t; b < nb; b += 256) cnt[b] = 0;
  __syncthreads();
  int ls[16], ld[16];
#pragma unroll
  for (int i = 0; i < 16; ++i) {
    int r = t + i * 256;
    if (r < n) {
      ls[i] = P.src[e0 + r];
      ld[i] = P.dst[e0 + r];
      atomicAdd(&cnt[ld[i] >> shift], 1);
    }
  }
  __syncthreads();
  for (int b = t; b < nb; b += 256) {
    int c = cnt[b];
    base[b] = c ? atomicAdd(&P.gcurb[b], c) : 0;
  }
  __syncthreads();
  for (int b = t; b < nb; b += 256) cnt[b] = 0;
  __syncthreads();
#pragma unroll
  for (int i = 0; i < 16; ++i) {
    int r = t + i * 256;
    if (r < n) {
      int b = ld[i] >> shift;
      int p = base[b] + atomicAdd(&cnt[b], 1);
      P.aux[p] = make_int2(ls[i], ld[i]);
    }
  }
}

// ---- pre GEMM body: Y[N,64](bf16) = x(fp32) @ W^T + bias ----
// Pipelined TPB_G tiles/block; W loaded fp32 + cvt in-register per wave.
struct PreSide {
  const float* X; const float* Wf; const float* bias; u16* Y;
  int N; int ntile; int nblk;
};
__device__ __forceinline__ void pre_body(const PreSide& P, int bid) {
  const int t = threadIdx.x;
  const int w = t >> 6, lane = t & 63;
  const int c = lane & 15, q = lane >> 4;
  int t0 = bid * TPB_G;
  int t1 = min(t0 + TPB_G, P.ntile);

  bf16x8 wf[4][2];
#pragma unroll
  for (int n = 0; n < 4; ++n)
#pragma unroll
    for (int kc = 0; kc < 2; ++kc) {
      const float* Wp = P.Wf + (n * 16 + c) * 64 + kc * 32 + q * 8;
      wf[n][kc] = pack_bf8(*(const f32x4*)Wp, *(const f32x4*)(Wp + 4));
    }
  float bv[4];
#pragma unroll
  for (int n = 0; n < 4; ++n) bv[n] = P.bias[n * 16 + c];

  const float* A1 = P.X;
  f32x4 rX[2][2][2], rY[2][2][2];  // [ms][kc][half]

  auto issue = [&](int tt, f32x4 (&buf)[2][2][2]) {
#pragma unroll
    for (int ms = 0; ms < 2; ++ms) {
      int row = tt * 128 + w * 32 + ms * 16 + c;
      int lr = min(row, P.N - 1);
#pragma unroll
      for (int kc = 0; kc < 2; ++kc) {
        const float* Af = A1 + (size_t)lr * 64 + kc * 32 + q * 8;
        buf[ms][kc][0] = *(const f32x4*)Af;
        buf[ms][kc][1] = *(const f32x4*)(Af + 4);
      }
    }
  };
  auto work = [&](int tt, f32x4 (&buf)[2][2][2]) {
    f32x4 acc[2][4];
#pragma unroll
    for (int ms = 0; ms < 2; ++ms)
#pragma unroll
      for (int n = 0; n < 4; ++n) acc[ms][n] = f32x4{0.f, 0.f, 0.f, 0.f};
    bf16x8 afr[2][2];
#pragma unroll
    for (int ms = 0; ms < 2; ++ms)
#pragma unroll
      for (int kc = 0; kc < 2; ++kc)
        afr[ms][kc] = pack_bf8(buf[ms][kc][0], buf[ms][kc][1]);
#pragma unroll
    for (int n = 0; n < 4; ++n)
#pragma unroll
      for (int ms = 0; ms < 2; ++ms)
#pragma unroll
        for (int kc = 0; kc < 2; ++kc)
          acc[ms][n] = __builtin_amdgcn_mfma_f32_16x16x32_bf16(afr[ms][kc], wf[n][kc],
                                                               acc[ms][n], 0, 0, 0);
    int row0 = tt * 128 + w * 32;
#pragma unroll
    for (int n = 0; n < 4; ++n) {
#pragma unroll
      for (int ms = 0; ms < 2; ++ms) {
#pragma unroll
        for (int r = 0; r < 4; ++r) {
          int row = row0 + ms * 16 + q * 4 + r;
          if (row < P.N) P.Y[(size_t)row * 64 + n * 16 + c] = f2bf(acc[ms][n][r] + bv[n]);
        }
      }
    }
  };

  int tt = t0;
  issue(tt, rX);
  for (; tt + 2 <= t1; tt += 2) {
    issue(tt + 1, rY);
    work(tt, rX);
    if (tt + 2 < t1) issue(tt + 2, rX);
    work(tt + 1, rY);
  }
  if (tt < t1) work(tt, rX);
}

// ---- mega dispatch: [pre_u | pre_i | binA_u2i | binA_i2u] ----
// pre is latency-bound at 2.3 waves/SIMD; binA's independent waves fill
// the idle slots (both latency-bound -> MLP adds).
__global__ __launch_bounds__(256) void k_pre_binA(PreSide PA, PreSide PB,
                                                  BinASide BA, BinASide BB,
                                                  int E, int gA) {
  int bid = blockIdx.x;
  if (bid < PA.nblk) { pre_body(PA, bid); return; }
  bid -= PA.nblk;
  if (bid < PB.nblk) { pre_body(PB, bid); return; }
  bid -= PB.nblk;
  if (bid < gA) { binA_body(BA, bid, E); return; }
  binA_body(BB, bid - gA, E);
}

// ---- Pass B (dual): per bucket -- LDS per-dst count + scan -> off[],
// then LDS-cursor scatter from slotted aux into compact csr ----
struct BinBSide {
  const int2* aux; const int* gcurb; const int* boff; int shift; int N;
  int* off; int* csr; int nblk;
};
__global__ __launch_bounds__(256) void k_dual_binB(BinBSide A, BinBSide B) {
  __shared__ int stage[4096];
  __shared__ int lcnt[512];
  __shared__ int sd[256];
  int b = blockIdx.x;
  const BinBSide& P = (b < A.nblk) ? A : B;
  if (b >= A.nblk) b -= A.nblk;
  int t = threadIdx.x;
  int d0 = b << P.shift;
  int d1 = min(d0 + (1 << P.shift), P.N);
  int nd = d1 - d0;
  size_t a0 = (size_t)b * SLOT_S;
  int r0 = P.boff[b];
  int RS = P.gcurb[b] - b * SLOT_S;
  for (int i = t; i < nd; i += 256) lcnt[i] = 0;
  __syncthreads();
  for (int i = t; i < RS; i += 256) {
    int2 p = P.aux[a0 + i];
    atomicAdd(&lcnt[p.y - d0], 1);
  }
  __syncthreads();
  // exclusive scan over nd (<=512) entries, 2 per thread
  int i0 = 2 * t, i1 = 2 * t + 1;
  int v0 = (i0 < nd) ? lcnt[i0] : 0;
  int v1 = (i1 < nd) ? lcnt[i1] : 0;
  int local = v0 + v1;
  sd[t] = local; __syncthreads();
  int sum = local;
  for (int o = 1; o < 256; o <<= 1) {
    int x = (t >= o) ? sd[t - o] : 0;
    __syncthreads();
    sum += x; sd[t] = sum;
    __syncthreads();
  }
  int run = sum - local;
  if (i0 < nd) { lcnt[i0] = run; P.off[d0 + i0] = r0 + run; }
  if (i1 < nd) { lcnt[i1] = run + v0; P.off[d0 + i1] = r0 + run + v0; }
  if (t == 0 && d1 == P.N) P.off[P.N] = r0 + RS;
  __syncthreads();
  if (RS <= 4096) {
    for (int i = t; i < RS; i += 256) {
      int2 p = P.aux[a0 + i];
      int pos = atomicAdd(&lcnt[p.y - d0], 1);
      stage[pos] = p.x;
    }
    __syncthreads();
    for (int i = t; i < RS; i += 256) P.csr[r0 + i] = stage[i];
  } else {
    for (int i = t; i < RS; i += 256) {
      int2 p = P.aux[a0 + i];
      int pos = atomicAdd(&lcnt[p.y - d0], 1);
      P.csr[r0 + pos] = p.x;
    }
  }
}

// ---- dual gather-mean: wave = 4 dsts; lane = (dst dd, u32x2 chunk c) ----
// R12: 8B row chunks per lane (16 lanes/dst). Full rounds unmasked (csr
// padded +16 zeros), 32-bit saddr addressing, pipelined idx prefetch.
struct GathSide {
  const u32* xs; const int* off; const int* csr; u32* msg; int N; int nblk;
};
__global__ __launch_bounds__(256) void k_dual_gather(GathSide A, GathSide B) {
  int bid = blockIdx.x;
  const GathSide& P = (bid < A.nblk) ? A : B;
  if (bid >= A.nblk) bid -= A.nblk;
  int lane = threadIdx.x & 63;
  int dd = lane >> 4, c = lane & 15;
  int d = bid * 16 + (int)(threadIdx.x >> 6) * 4 + dd;
  if (d >= P.N) return;
  int beg = P.off[d];
  int deg = P.off[d + 1] - beg;
  const char* xsb = (const char*)P.xs;
  const int* cp = P.csr + beg;
  u32 c8 = (u32)(c << 3);
  f32x2 s0 = {0.f, 0.f}, s1 = {0.f, 0.f};
  if (deg > 0) {
    int idx[8];
#pragma unroll
    for (int i = 0; i < 8; ++i) idx[i] = cp[i];  // overread <=7: pad-safe
    int j = 0;
    for (; j + 8 <= deg; j += 8) {  // full rounds, no mask
      u32x2 p[8];
#pragma unroll
      for (int i = 0; i < 8; ++i)
        p[i] = *(const u32x2*)(xsb + (size_t)((((u32)idx[i]) << 7) | c8));
#pragma unroll
      for (int i = 0; i < 8; ++i) idx[i] = cp[j + 8 + i];  // overread <=15: pad-safe
#pragma unroll
      for (int i = 0; i < 8; ++i) {
        f32x2 v0 = {blo(p[i][0]), bhi(p[i][0])};
        f32x2 v1 = {blo(p[i][1]), bhi(p[i][1])};
        s0 += v0; s1 += v1;
      }
    }
    if (j < deg) {  // single masked tail round (idx already loaded)
      u32x2 p[8];
#pragma unroll
      for (int i = 0; i < 8; ++i)
        p[i] = *(const u32x2*)(xsb + (size_t)((((u32)idx[i]) << 7) | c8));
#pragma unroll
      for (int i = 0; i < 8; ++i) {
        float m = (j + i < deg) ? 1.0f : 0.0f;
        f32x2 v0 = {blo(p[i][0]) * m, bhi(p[i][0]) * m};
        f32x2 v1 = {blo(p[i][1]) * m, bhi(p[i][1]) * m};
        s0 += v0; s1 += v1;
      }
    }
  }
  float sc = 1.0f / fmaxf((float)deg, 1.0f);
  u32x2 outv;
  outv[0] = (u32)f2bf(s0[0] * sc) | ((u32)f2bf(s0[1] * sc) << 16);
  outv[1] = (u32)f2bf(s1[0] * sc) | ((u32)f2bf(s1[1] * sc) << 16);
  *(u32x2*)((char*)P.msg + (((size_t)d) << 7) + c8) = outv;
}

// ---- conv GEMM: Y[N,64](bf16) = relu( A1@Wrel^T + A2@(Wroot+I)^T + b )
// Pipelined TPB_G tiles; fp32 W + in-register cvt (+I fold, static idx);
// unconditional clamped A loads.
struct ConvSide {
  const u16* A1; const u16* A2; const float* W1f; const float* W2f;
  const float* bias; u16* Y; int N; int ntile; int nblk;
};
__device__ __forceinline__ void conv_body(const ConvSide& P, int bid) {
  const int t = threadIdx.x;
  const int w = t >> 6, lane = t & 63;
  const int c = lane & 15, q = lane >> 4;
  int t0 = bid * TPB_G;
  int t1 = min(t0 + TPB_G, P.ntile);

  bf16x8 wf[2][4][2];
#pragma unroll
  for (int hh = 0; hh < 2; ++hh)
#pragma unroll
    for (int n = 0; n < 4; ++n)
#pragma unroll
      for (int kc = 0; kc < 2; ++kc) {
        const float* Wp = (hh ? P.W2f : P.W1f) + (n * 16 + c) * 64 + kc * 32 + q * 8;
        f32x4 lo = *(const f32x4*)Wp;
        f32x4 hi = *(const f32x4*)(Wp + 4);
        if (hh) {  // wroot + I: diag row==col, static-index predicated adds
          int jd = n * 16 + c - kc * 32 - q * 8;
#pragma unroll
          for (int j = 0; j < 4; ++j) {
            if (jd == j) lo[j] += 1.0f;
            if (jd == j + 4) hi[j] += 1.0f;
          }
        }
        wf[hh][n][kc] = pack_bf8(lo, hi);
      }
  float bv[4];
#pragma unroll
  for (int n = 0; n < 4; ++n) bv[n] = P.bias[n * 16 + c];

  const u16* A1 = P.A1;
  const u16* A2 = P.A2;

  bf16x8 aX[2][2][2], aY[2][2][2];  // [hh][ms][kc]

  auto issue = [&](int tt, bf16x8 (&buf)[2][2][2]) {
#pragma unroll
    for (int ms = 0; ms < 2; ++ms) {
      int row = tt * 128 + w * 32 + ms * 16 + c;
      int lr = min(row, P.N - 1);
#pragma unroll
      for (int kc = 0; kc < 2; ++kc) {
        buf[0][ms][kc] = *(const bf16x8*)(A1 + (size_t)lr * 64 + kc * 32 + q * 8);
        buf[1][ms][kc] = *(const bf16x8*)(A2 + (size_t)lr * 64 + kc * 32 + q * 8);
      }
    }
  };
  auto work = [&](int tt, bf16x8 (&buf)[2][2][2]) {
    f32x4 acc[2][4];
#pragma unroll
    for (int ms = 0; ms < 2; ++ms)
#pragma unroll
      for (int n = 0; n < 4; ++n) acc[ms][n] = f32x4{0.f, 0.f, 0.f, 0.f};
#pragma unroll
    for (int hh = 0; hh < 2; ++hh)
#pragma unroll
      for (int n = 0; n < 4; ++n)
#pragma unroll
        for (int ms = 0; ms < 2; ++ms)
#pragma unroll
          for (int kc = 0; kc < 2; ++kc)
            acc[ms][n] = __builtin_amdgcn_mfma_f32_16x16x32_bf16(buf[hh][ms][kc], wf[hh][n][kc],
                                                                 acc[ms][n], 0, 0, 0);
    int row0 = tt * 128 + w * 32;
#pragma unroll
    for (int n = 0; n < 4; ++n) {
#pragma unroll
      for (int ms = 0; ms < 2; ++ms) {
#pragma unroll
        for (int r = 0; r < 4; ++r) {
          int row = row0 + ms * 16 + q * 4 + r;
          if (row < P.N)
            P.Y[(size_t)row * 64 + n * 16 + c] = f2bf(fmaxf(acc[ms][n][r] + bv[n], 0.f));
        }
      }
    }
  };

  int tt = t0;
  issue(tt, aX);
  for (; tt + 2 <= t1; tt += 2) {
    issue(tt + 1, aY);
    work(tt, aX);
    if (tt + 2 < t1) issue(tt + 2, aX);
    work(tt + 1, aY);
  }
  if (tt < t1) work(tt, aX);
}
__global__ __launch_bounds__(256) void k_dual_conv_gemm(ConvSide A, ConvSide B) {
  if ((int)blockIdx.x < A.nblk) conv_body(A, blockIdx.x);
  else conv_body(B, blockIdx.x - A.nblk);
}

// ---- dual MFMA post linear: Y[N,32](fp32) = A(bf16) @ W[32,64]^T + bias ----
struct PostSide {
  const u16* A; const float* Wf; const float* bias; float* Y; int N; int nblk;
};
__device__ __forceinline__ void postlin_body(const PostSide& P, int bid) {
  const int t = threadIdx.x;
  const int w = t >> 6, lane = t & 63;
  const int c = lane & 15, q = lane >> 4;
  const int row0 = bid * 128 + w * 32;

  f32x4 acc[2][2];
#pragma unroll
  for (int ms = 0; ms < 2; ++ms)
#pragma unroll
    for (int n = 0; n < 2; ++n) acc[ms][n] = f32x4{0.f, 0.f, 0.f, 0.f};

  bf16x8 bfr[2][2];
#pragma unroll
  for (int n = 0; n < 2; ++n)
#pragma unroll
    for (int kc = 0; kc < 2; ++kc) {
      const float* Wp = P.Wf + (n * 16 + c) * 64 + kc * 32 + q * 8;
      bfr[n][kc] = pack_bf8(*(const f32x4*)Wp, *(const f32x4*)(Wp + 4));
    }
  bf16x8 afr[2][2];
#pragma unroll
  for (int ms = 0; ms < 2; ++ms) {
    int row = row0 + ms * 16 + c;
    int lr = min(row, P.N - 1);
#pragma unroll
    for (int kc = 0; kc < 2; ++kc)
      afr[ms][kc] = *(const bf16x8*)(P.A + (size_t)lr * 64 + kc * 32 + q * 8);
  }
#pragma unroll
  for (int n = 0; n < 2; ++n)
#pragma unroll
    for (int ms = 0; ms < 2; ++ms)
#pragma unroll
      for (int kc = 0; kc < 2; ++kc)
        acc[ms][n] = __builtin_amdgcn_mfma_f32_16x16x32_bf16(afr[ms][kc], bfr[n][kc],
                                                             acc[ms][n], 0, 0, 0);
#pragma unroll
  for (int n = 0; n < 2; ++n) {
    float bv = P.bias[n * 16 + c];
#pragma unroll
    for (int ms = 0; ms < 2; ++ms) {
#pragma unroll
      for (int r = 0; r < 4; ++r) {
        int row = row0 + ms * 16 + q * 4 + r;
        if (row < P.N) P.Y[(size_t)row * 32 + n * 16 + c] = acc[ms][n][r] + bv;
      }
    }
  }
}
__global__ __launch_bounds__(256) void k_dual_postlin(PostSide A, PostSide B) {
  if ((int)blockIdx.x < A.nblk) postlin_body(A, blockIdx.x);
  else postlin_body(B, blockIdx.x - A.nblk);
}

extern "C" void kernel_launch(void* const* d_in, const int* in_sizes, int n_in,
                              void* d_out, int out_size, void* d_ws, size_t ws_size,
                              hipStream_t stream) {
  const float* x_user = (const float*)d_in[0];
  const float* x_item = (const float*)d_in[1];
  const int* ei_u2i = (const int*)d_in[2];
  const int* ei_i2u = (const int*)d_in[3];

  const int NU = in_sizes[0] / FDIM;
  const int NI = in_sizes[1] / FDIM;
  const int E = in_sizes[2] / 2;

  const int SH_I = 8, SH_U = 9;
  const int nbI = (NI + (1 << SH_I) - 1) >> SH_I;
  const int nbU = (NU + (1 << SH_U) - 1) >> SH_U;

  // ---- workspace ----
  u16* wsu = (u16*)d_ws;
  u16* h_u = wsu;   wsu += (size_t)NU * FDIM;
  u16* h_i = wsu;   wsu += (size_t)NI * FDIM;
  u16* x1_u = wsu;  wsu += (size_t)NU * FDIM;
  u16* x1_i = wsu;  wsu += (size_t)NI * FDIM;
  u16* msg_i = wsu; wsu += (size_t)NI * FDIM;
  u16* msg_u = wsu; wsu += (size_t)NU * FDIM;
  int2* aux_i = (int2*)wsu;
  int2* aux_u = aux_i + (size_t)nbI * SLOT_S;
  int* wsi = (int*)(aux_u + (size_t)nbU * SLOT_S);
  int* off_i = wsi;    wsi += NI + 1;
  int* off_u = wsi;    wsi += NU + 1;
  int* boff_i = wsi;   wsi += nbI + 1;
  int* boff_u = wsi;   wsi += nbU + 1;
  int* gcurb_i = wsi;  wsi += 512;
  int* gcurb_u = wsi;  wsi += 512;
  int* csr_u2i = wsi;  wsi += E + 16;  // +16 pad for unclamped overread
  int* csr_i2u = wsi;  wsi += E + 16;

  const int* u2i_src = ei_u2i;
  const int* u2i_dst = ei_u2i + E;
  const int* i2u_src = ei_i2u;
  const int* i2u_dst = ei_i2u + E;

  const int gA = (E + PA_C - 1) / PA_C;
  const int tU = (NU + 127) / 128;
  const int tI = (NI + 127) / 128;
  const int blkU = (tU + TPB_G - 1) / TPB_G;
  const int blkI = (tI + TPB_G - 1) / TPB_G;
  const int gGI = (NI + 15) / 16;
  const int gGU = (NU + 15) / 16;

  k_init_gcurb<<<(nbI + nbU + 255) / 256, 256, 0, stream>>>(gcurb_i, nbI, gcurb_u, nbU,
                                                            csr_u2i + E, csr_i2u + E);

  // ---- mega dispatch: pre linears (fp32 W direct) + binA edge binning ----
  {
    PreSide pa{x_user, (const float*)d_in[4], (const float*)d_in[5], h_u, NU, tU, blkU};
    PreSide pb{x_item, (const float*)d_in[6], (const float*)d_in[7], h_i, NI, tI, blkI};
    BinASide ba{u2i_src, u2i_dst, SH_I, nbI, gcurb_i, aux_i};
    BinASide bb{i2u_src, i2u_dst, SH_U, nbU, gcurb_u, aux_u};
    k_pre_binA<<<blkU + blkI + 2 * gA, 256, 0, stream>>>(pa, pb, ba, bb, E, gA);
  }

  k_bscan2<<<1, 512, 0, stream>>>(gcurb_i, nbI, gcurb_u, nbU, boff_i, boff_u);
  {
    BinBSide a{aux_i, gcurb_i, boff_i, SH_I, NI, off_i, csr_u2i, nbI};
    BinBSide b{aux_u, gcurb_u, boff_u, SH_U, NU, off_u, csr_i2u, nbU};
    k_dual_binB<<<nbI + nbU, 256, 0, stream>>>(a, b);
  }

  // ---- layer 1: both gathers in one dispatch, both convs in one ----
  {
    GathSide a{(const u32*)h_u, off_i, csr_u2i, (u32*)msg_i, NI, gGI};
    GathSide b{(const u32*)h_i, off_u, csr_i2u, (u32*)msg_u, NU, gGU};
    k_dual_gather<<<gGI + gGU, 256, 0, stream>>>(a, b);
  }
  {
    ConvSide a{msg_i, h_i, (const float*)d_in[8], (const float*)d_in[10],
               (const float*)d_in[9], x1_i, NI, tI, blkI};
    ConvSide b{msg_u, h_u, (const float*)d_in[11], (const float*)d_in[13],
               (const float*)d_in[12], x1_u, NU, tU, blkU};
    k_dual_conv_gemm<<<blkI + blkU, 256, 0, stream>>>(a, b);
  }

  // ---- layer 2 (outputs overwrite h_i / h_u) ----
  {
    GathSide a{(const u32*)x1_u, off_i, csr_u2i, (u32*)msg_i, NI, gGI};
    GathSide b{(const u32*)x1_i, off_u, csr_i2u, (u32*)msg_u, NU, gGU};
    k_dual_gather<<<gGI + gGU, 256, 0, stream>>>(a, b);
  }
  {
    ConvSide a{msg_i, x1_i, (const float*)d_in[14], (const float*)d_in[16],
               (const float*)d_in[15], h_i, NI, tI, blkI};
    ConvSide b{msg_u, x1_u, (const float*)d_in[17], (const float*)d_in[19],
               (const float*)d_in[18], h_u, NU, tU, blkU};
    k_dual_conv_gemm<<<blkI + blkU, 256, 0, stream>>>(a, b);
  }

  // ---- post linears (dual) -> fp32 d_out = [out_u | out_i] ----
  {
    float* out = (float*)d_out;
    PostSide a{h_u, (const float*)d_in[20], (const float*)d_in[21], out, NU, tU};
    PostSide b{h_i, (const float*)d_in[22], (const float*)d_in[23],
               out + (size_t)NU * 32, NI, tI};
    k_dual_postlin<<<tU + tI, 256, 0, stream>>>(a, b);
  }
}